// Round 4
// baseline (184.676 us; speedup 1.0000x reference)
//
#include <hip/hip_runtime.h>

#define NPTS 1000000
#define OUT_STRIDE (9 * NPTS)

// Scales order: [2, 4, 8, 16, 1]; dims = ceil(SPATIAL/scale)+1
constexpr int   kSX[5]  = {241, 121, 61, 31, 481};
constexpr int   kSY[5]  = {181,  91, 46, 24, 361};
constexpr int   kSZ[5]  = { 17,   9,  5,  3,  33};
constexpr float kSSX[5] = {240.f, 120.f, 60.f, 30.f, 480.f};
constexpr float kSSY[5] = {180.f,  90.f, 45.f, 23.f, 360.f};
constexpr float kSSZ[5] = { 16.f,   8.f,  4.f,  2.f,  32.f};
// word-bases of each scale's bitmap region (keyspace/32, rounded up to 64)
constexpr int kWB[5] = {0, 92736, 105152, 106944, 107264};
#define W_TOTAL 823552        // 107264 + 716288 (== 4 * 205888)
#define SCAN_BLOCKS 403       // ceil(W_TOTAL / 2048)

// LDS-resident scales: s=1 (scale4), s=2 (scale8), s=3 (scale16)
#define LW1 12388   // ceil(4*121*91*9 / 32)
#define LW2 1754    // ceil(4*61*46*5 / 32)
#define LW3 279     // ceil(4*31*24*3 / 32)
#define LWT (LW1 + LW2 + LW3)   // 14421 words = 57684 B
#define MF_BLK 1024
#define MF_NB  512

// ---- fast zero of the bitmap (rocclr fillBuffer was 107 us @ 30 GB/s)
__global__ void zero_kernel(uint4* __restrict__ p) {
  int i = blockIdx.x * 256 + threadIdx.x;
  if (i < W_TOTAL / 4) p[i] = make_uint4(0u, 0u, 0u, 0u);
}

// ---- mark: LDS bitmaps for scales 4/8/16; unconditional fire-and-forget
//      global atomics for scales 2/1
__global__ __launch_bounds__(MF_BLK) void mark_fill2_kernel(
    const float4* __restrict__ pts, const int* __restrict__ bidx,
    int* __restrict__ out, unsigned* __restrict__ bits,
    unsigned* __restrict__ priv) {
  __shared__ unsigned lb[LWT];
  for (int w = threadIdx.x; w < LWT; w += MF_BLK) lb[w] = 0u;
  __syncthreads();

  const float PI_F = 3.14159265f;
  const float CROP1 = PI_F + PI_F;
  constexpr int kLB[5] = {0, 0, LW1, LW1 + LW2, 0};

  for (int i = blockIdx.x * MF_BLK + threadIdx.x; i < NPTS; i += MF_NB * MF_BLK) {
    float4 p = pts[i];
    float rho = __fsqrt_rn(__fadd_rn(__fmul_rn(p.x, p.x), __fmul_rn(p.y, p.y)));
    float phi = (float)atan2((double)p.y, (double)p.x);
    float zz = p.z;
    int b = bidx[i];
#pragma unroll
    for (int s = 0; s < 5; ++s) {
      int ix = (int)__fdiv_rn(__fmul_rn(kSSX[s], rho), 50.0f);
      int iy = (int)__fdiv_rn(__fmul_rn(kSSY[s], __fsub_rn(phi, -PI_F)), CROP1);
      int iz = (int)__fdiv_rn(__fmul_rn(kSSZ[s], __fsub_rn(zz, -4.0f)), 6.0f);
      int key = ((b * kSX[s] + ix) * kSY[s] + iy) * kSZ[s] + iz;

      ((int4*)(out + (size_t)s * OUT_STRIDE))[i] = make_int4(b, ix, iy, iz);

      unsigned m = 1u << (key & 31);
      if (s == 0 || s == 4) {
        atomicOr(&bits[(unsigned)kWB[s] + ((unsigned)key >> 5)], m);
      } else {
        atomicOr(&lb[kLB[s] + ((unsigned)key >> 5)], m);
      }
    }
  }
  __syncthreads();
  unsigned* pb = priv + (size_t)blockIdx.x * LWT;
  for (int w = threadIdx.x; w < LWT; w += MF_BLK) pb[w] = lb[w];
}

// OR-reduce the 512 private bitmaps into the global bitmap regions
__global__ void reduce_kernel(const unsigned* __restrict__ priv,
                              unsigned* __restrict__ bits) {
  int w = blockIdx.x * 256 + threadIdx.x;
  if (w >= LWT) return;
  unsigned acc = 0;
#pragma unroll 8
  for (int c = 0; c < MF_NB; ++c) acc |= priv[(size_t)c * LWT + w];
  int g;
  if (w < LW1) g = kWB[1] + w;
  else if (w < LW1 + LW2) g = kWB[2] + (w - LW1);
  else g = kWB[3] + (w - LW1 - LW2);
  bits[g] = acc;
}

// ---- scan stage 1: per-word exclusive popcount prefix within 2048-word blocks
__global__ void scan1_kernel(const unsigned* __restrict__ bits,
                             unsigned* __restrict__ wp,
                             unsigned* __restrict__ bsums) {
  __shared__ unsigned sh[256];
  int tid = threadIdx.x;
  int base = blockIdx.x * 2048 + tid * 8;
  unsigned c[8];
  unsigned sum = 0;
#pragma unroll
  for (int j = 0; j < 8; ++j) {
    c[j] = sum;
    int w = base + j;
    sum += (w < W_TOTAL) ? (unsigned)__popc(bits[w]) : 0u;
  }
  sh[tid] = sum;
  __syncthreads();
  for (int off = 1; off < 256; off <<= 1) {
    unsigned v = (tid >= off) ? sh[tid - off] : 0u;
    __syncthreads();
    sh[tid] += v;
    __syncthreads();
  }
  unsigned tbase = sh[tid] - sum;
#pragma unroll
  for (int j = 0; j < 8; ++j) {
    int w = base + j;
    if (w < W_TOTAL) wp[w] = tbase + c[j];
  }
  if (tid == 0) bsums[blockIdx.x] = sh[255];
}

// ---- scan stage 2: exclusive scan of block sums; also store grand total
__global__ void scan2_kernel(unsigned* __restrict__ bsums) {
  __shared__ unsigned sh[1024];
  int t = threadIdx.x;
  unsigned v = (t < SCAN_BLOCKS) ? bsums[t] : 0u;
  sh[t] = v;
  __syncthreads();
  for (int off = 1; off < 1024; off <<= 1) {
    unsigned u = (t >= off) ? sh[t - off] : 0u;
    __syncthreads();
    sh[t] += u;
    __syncthreads();
  }
  if (t < SCAN_BLOCKS) bsums[t] = sh[t] - v;  // exclusive
  if (t == SCAN_BLOCKS - 1) bsums[512] = sh[t];  // inclusive grand total
}

// full prefix of word w = wp[w] + bsums[w >> 11]
__device__ __forceinline__ unsigned fullp(const unsigned* wp, const unsigned* bs, int w) {
  return wp[w] + bs[w >> 11];
}

__device__ __forceinline__ unsigned region_count(int s, const unsigned* wp,
                                                 const unsigned* bs) {
  unsigned lo = fullp(wp, bs, kWB[s]);
  unsigned hi = (s == 4) ? bs[512] : fullp(wp, bs, kWB[s + 1]);
  return hi - lo;
}

// ---- pad fill: rows >= uniq_count get the fill_value=-1 decode
__global__ void padfill_kernel(const unsigned* __restrict__ wp,
                               const unsigned* __restrict__ bsums,
                               int* __restrict__ out) {
  int idx = blockIdx.x * 256 + threadIdx.x;
  if (idx >= 5 * NPTS) return;
  int s = idx / NPTS;
  int r = idx - s * NPTS;
  unsigned uniq = region_count(s, wp, bsums);
  if ((unsigned)r < uniq) return;
  ((int4*)(out + (size_t)s * OUT_STRIDE + 5 * NPTS))[r] =
      make_int4(-1, kSZ[s] - 1, kSY[s] - 1, kSX[s] - 1);
}

// ---- scatter: decompose each present key into coors[rank]
__global__ void scatter_kernel(const unsigned* __restrict__ bits,
                               const unsigned* __restrict__ wp,
                               const unsigned* __restrict__ bsums,
                               int* __restrict__ out) {
  int w = blockIdx.x * 256 + threadIdx.x;
  if (w >= W_TOTAL) return;
  unsigned word = bits[w];
  if (!word) return;
  int s, wb;
  unsigned sx, sy, sz;
  if      (w >= kWB[4]) { s = 4; wb = kWB[4]; sx = 481; sy = 361; sz = 33; }
  else if (w >= kWB[3]) { s = 3; wb = kWB[3]; sx = 31;  sy = 24;  sz = 3;  }
  else if (w >= kWB[2]) { s = 2; wb = kWB[2]; sx = 61;  sy = 46;  sz = 5;  }
  else if (w >= kWB[1]) { s = 1; wb = kWB[1]; sx = 121; sy = 91;  sz = 9;  }
  else                  { s = 0; wb = 0;      sx = 241; sy = 181; sz = 17; }
  unsigned rank = fullp(wp, bsums, w) - fullp(wp, bsums, wb);
  int4* coors = (int4*)(out + (size_t)s * OUT_STRIDE + 5 * NPTS);
  unsigned kbase = (unsigned)(w - wb) * 32u;
  while (word) {
    int bit = __ffs(word) - 1;
    word &= word - 1;
    unsigned k = kbase + (unsigned)bit;
    unsigned z = k % sz; unsigned t = k / sz;
    unsigned y = t % sy; t /= sy;
    unsigned x = t % sx; unsigned b = t / sx;
    coors[rank++] = make_int4((int)b, (int)z, (int)y, (int)x);
  }
}

// ---- inverse: recompute keys from points, rank via bitmap prefix
__global__ void inv_kernel(const float4* __restrict__ pts,
                           const int* __restrict__ bidx,
                           const unsigned* __restrict__ bits,
                           const unsigned* __restrict__ wp,
                           const unsigned* __restrict__ bsums,
                           int* __restrict__ out) {
  int i = blockIdx.x * blockDim.x + threadIdx.x;
  if (i >= NPTS) return;
  float4 p = pts[i];
  float rho = __fsqrt_rn(__fadd_rn(__fmul_rn(p.x, p.x), __fmul_rn(p.y, p.y)));
  float phi = (float)atan2((double)p.y, (double)p.x);
  float zz = p.z;
  int b = bidx[i];
  const float PI_F = 3.14159265f;
  const float CROP1 = PI_F + PI_F;
#pragma unroll
  for (int s = 0; s < 5; ++s) {
    int ix = (int)__fdiv_rn(__fmul_rn(kSSX[s], rho), 50.0f);
    int iy = (int)__fdiv_rn(__fmul_rn(kSSY[s], __fsub_rn(phi, -PI_F)), CROP1);
    int iz = (int)__fdiv_rn(__fmul_rn(kSSZ[s], __fsub_rn(zz, -4.0f)), 6.0f);
    unsigned k = (unsigned)(((b * kSX[s] + ix) * kSY[s] + iy) * kSZ[s] + iz);
    int w = kWB[s] + (int)(k >> 5);
    unsigned r = fullp(wp, bsums, w) - fullp(wp, bsums, kWB[s]) +
                 (unsigned)__popc(bits[w] & ((1u << (k & 31)) - 1u));
    out[(size_t)s * OUT_STRIDE + 4 * NPTS + i] = (int)r;
  }
}

extern "C" void kernel_launch(void* const* d_in, const int* in_sizes, int n_in,
                              void* d_out, int out_size, void* d_ws, size_t ws_size,
                              hipStream_t stream) {
  const float4* pts = (const float4*)d_in[0];
  const int* bidx = (const int*)d_in[1];
  int* out = (int*)d_out;

  unsigned* bits  = (unsigned*)d_ws;          // W_TOTAL u32 (3.3 MB)
  unsigned* wp    = bits + W_TOTAL;           // W_TOTAL u32 (3.3 MB)
  unsigned* bsums = wp + W_TOTAL;             // 1024 u32 ([512] = grand total)
  unsigned* priv  = bsums + 1024;             // 512*LWT u32 (29.5 MB)

  zero_kernel<<<(W_TOTAL / 4 + 255) / 256, 256, 0, stream>>>((uint4*)bits);
  mark_fill2_kernel<<<MF_NB, MF_BLK, 0, stream>>>(pts, bidx, out, bits, priv);
  reduce_kernel<<<(LWT + 255) / 256, 256, 0, stream>>>(priv, bits);
  scan1_kernel<<<SCAN_BLOCKS, 256, 0, stream>>>(bits, wp, bsums);
  scan2_kernel<<<1, 1024, 0, stream>>>(bsums);
  padfill_kernel<<<(5 * NPTS + 255) / 256, 256, 0, stream>>>(wp, bsums, out);
  scatter_kernel<<<(W_TOTAL + 255) / 256, 256, 0, stream>>>(bits, wp, bsums, out);
  inv_kernel<<<(NPTS + 255) / 256, 256, 0, stream>>>(pts, bidx, bits, wp, bsums, out);
}

// Round 5
// 139.836 us; speedup vs baseline: 1.3207x; 1.3207x over previous
//
#include <hip/hip_runtime.h>

#define NPTS 1000000
#define OUT_STRIDE (9 * NPTS)

// Scales order: [2, 4, 8, 16, 1]; dims = ceil(SPATIAL/scale)+1
constexpr int   kSX[5]  = {241, 121, 61, 31, 481};
constexpr int   kSY[5]  = {181,  91, 46, 24, 361};
constexpr int   kSZ[5]  = { 17,   9,  5,  3,  33};
constexpr float kSSX[5] = {240.f, 120.f, 60.f, 30.f, 480.f};
constexpr float kSSY[5] = {180.f,  90.f, 45.f, 23.f, 360.f};
constexpr float kSSZ[5] = { 16.f,   8.f,  4.f,  2.f,  32.f};
// word-bases of each scale's bitmap region (keyspace/32, rounded up to 64)
constexpr int kWB[5] = {0, 92736, 105152, 106944, 107264};
#define W_TOTAL 823552        // 107264 + 716288
#define SCAN_BLOCKS 403       // ceil(W_TOTAL / 2048)

// byte-map geometry for scales s=0 (scale2) and s=4 (scale1)
#define BM0_WORDS 92736                    // == kWB[1]
#define BM4_WORDS 716288                   // == W_TOTAL - kWB[4]
#define BM_BYTES  ((BM0_WORDS + BM4_WORDS) * 32)   // 25,888,768 B
#define BM_U4     (BM_BYTES / 16)          // 1,618,048 uint4

// LDS-resident scales: s=1 (scale4), s=2 (scale8), s=3 (scale16)
#define LW1 12388   // ceil(4*121*91*9 / 32)
#define LW2 1754    // ceil(4*61*46*5 / 32)
#define LW3 279     // ceil(4*31*24*3 / 32)
#define LWT (LW1 + LW2 + LW3)   // 14421 words = 57684 B
#define MF_BLK 1024
#define MF_NB  256

// ---- zero the byte map (bits[] needs no zeroing: reduce+scan1 write all of it)
__global__ void zero_kernel(uint4* __restrict__ p) {
  int i = blockIdx.x * 256 + threadIdx.x;
  if (i < BM_U4) p[i] = make_uint4(0u, 0u, 0u, 0u);
}

// ---- mark: LDS bitmaps for scales 4/8/16; idempotent byte stores for 2/1
__global__ __launch_bounds__(MF_BLK) void mark_fill2_kernel(
    const float4* __restrict__ pts, const int* __restrict__ bidx,
    int* __restrict__ out, unsigned char* __restrict__ bytemap,
    unsigned* __restrict__ priv) {
  __shared__ unsigned lb[LWT];
  for (int w = threadIdx.x; w < LWT; w += MF_BLK) lb[w] = 0u;
  __syncthreads();

  const float PI_F = 3.14159265f;
  const float CROP1 = PI_F + PI_F;
  constexpr int kLB[5] = {0, 0, LW1, LW1 + LW2, 0};
  unsigned char* __restrict__ by0 = bytemap;                       // s=0 region
  unsigned char* __restrict__ by4 = bytemap + BM0_WORDS * 32;      // s=4 region

  for (int i = blockIdx.x * MF_BLK + threadIdx.x; i < NPTS; i += MF_NB * MF_BLK) {
    float4 p = pts[i];
    float rho = __fsqrt_rn(__fadd_rn(__fmul_rn(p.x, p.x), __fmul_rn(p.y, p.y)));
    float phi = (float)atan2((double)p.y, (double)p.x);
    float zz = p.z;
    int b = bidx[i];
#pragma unroll
    for (int s = 0; s < 5; ++s) {
      int ix = (int)__fdiv_rn(__fmul_rn(kSSX[s], rho), 50.0f);
      int iy = (int)__fdiv_rn(__fmul_rn(kSSY[s], __fsub_rn(phi, -PI_F)), CROP1);
      int iz = (int)__fdiv_rn(__fmul_rn(kSSZ[s], __fsub_rn(zz, -4.0f)), 6.0f);
      int key = ((b * kSX[s] + ix) * kSY[s] + iy) * kSZ[s] + iz;

      ((int4*)(out + (size_t)s * OUT_STRIDE))[i] = make_int4(b, ix, iy, iz);

      if (s == 0)      by0[key] = 1;   // plain store, idempotent, race-benign
      else if (s == 4) by4[key] = 1;
      else atomicOr(&lb[kLB[s] + ((unsigned)key >> 5)], 1u << (key & 31));
    }
  }
  __syncthreads();
  unsigned* pb = priv + (size_t)blockIdx.x * LWT;
  for (int w = threadIdx.x; w < LWT; w += MF_BLK) pb[w] = lb[w];
}

// OR-reduce the private bitmaps into the global bitmap regions (s1-s3)
__global__ void reduce_kernel(const unsigned* __restrict__ priv,
                              unsigned* __restrict__ bits) {
  int w = blockIdx.x * 256 + threadIdx.x;
  if (w >= LWT) return;
  unsigned acc = 0;
#pragma unroll 8
  for (int c = 0; c < MF_NB; ++c) acc |= priv[(size_t)c * LWT + w];
  int g;
  if (w < LW1) g = kWB[1] + w;
  else if (w < LW1 + LW2) g = kWB[2] + (w - LW1);
  else g = kWB[3] + (w - LW1 - LW2);
  bits[g] = acc;
}

// 32 presence-bytes (each 0/1) -> 32-bit mask
__device__ __forceinline__ unsigned nib(unsigned u) {
  return (u | (u >> 7) | (u >> 14) | (u >> 21)) & 0xFu;
}
__device__ __forceinline__ unsigned word_from_bytes(const uint4* p) {
  uint4 a = p[0], b = p[1];
  return nib(a.x) | (nib(a.y) << 4) | (nib(a.z) << 8) | (nib(a.w) << 12) |
         (nib(b.x) << 16) | (nib(b.y) << 20) | (nib(b.z) << 24) | (nib(b.w) << 28);
}

// ---- scan stage 1: convert byte-map regions to bit words + popcount prefix
__global__ void scan1_kernel(const uint4* __restrict__ bytemap,
                             unsigned* __restrict__ bits,
                             unsigned* __restrict__ wp,
                             unsigned* __restrict__ bsums) {
  __shared__ unsigned sh[256];
  int tid = threadIdx.x;
  int base = blockIdx.x * 2048 + tid * 8;
  unsigned c[8];
  unsigned sum = 0;
#pragma unroll
  for (int j = 0; j < 8; ++j) {
    c[j] = sum;
    int w = base + j;
    unsigned m = 0;
    if (w < W_TOTAL) {
      if (w < kWB[1]) {                       // s=0: from byte map
        m = word_from_bytes(bytemap + (size_t)w * 2);
        bits[w] = m;
      } else if (w >= kWB[4]) {               // s=4: from byte map
        m = word_from_bytes(bytemap + (size_t)(BM0_WORDS + (w - kWB[4])) * 2);
        bits[w] = m;
      } else {                                // s=1..3: written by reduce
        m = bits[w];
      }
    }
    sum += (unsigned)__popc(m);
  }
  sh[tid] = sum;
  __syncthreads();
  for (int off = 1; off < 256; off <<= 1) {
    unsigned v = (tid >= off) ? sh[tid - off] : 0u;
    __syncthreads();
    sh[tid] += v;
    __syncthreads();
  }
  unsigned tbase = sh[tid] - sum;
#pragma unroll
  for (int j = 0; j < 8; ++j) {
    int w = base + j;
    if (w < W_TOTAL) wp[w] = tbase + c[j];
  }
  if (tid == 0) bsums[blockIdx.x] = sh[255];
}

// ---- scan stage 2: exclusive scan of block sums; also store grand total
__global__ void scan2_kernel(unsigned* __restrict__ bsums) {
  __shared__ unsigned sh[1024];
  int t = threadIdx.x;
  unsigned v = (t < SCAN_BLOCKS) ? bsums[t] : 0u;
  sh[t] = v;
  __syncthreads();
  for (int off = 1; off < 1024; off <<= 1) {
    unsigned u = (t >= off) ? sh[t - off] : 0u;
    __syncthreads();
    sh[t] += u;
    __syncthreads();
  }
  if (t < SCAN_BLOCKS) bsums[t] = sh[t] - v;  // exclusive
  if (t == SCAN_BLOCKS - 1) bsums[512] = sh[t];  // inclusive grand total
}

// full prefix of word w = wp[w] + bsums[w >> 11]
__device__ __forceinline__ unsigned fullp(const unsigned* wp, const unsigned* bs, int w) {
  return wp[w] + bs[w >> 11];
}

__device__ __forceinline__ unsigned region_count(int s, const unsigned* wp,
                                                 const unsigned* bs) {
  unsigned lo = fullp(wp, bs, kWB[s]);
  unsigned hi = (s == 4) ? bs[512] : fullp(wp, bs, kWB[s + 1]);
  return hi - lo;
}

// ---- pad fill: rows >= uniq_count get the fill_value=-1 decode
__global__ void padfill_kernel(const unsigned* __restrict__ wp,
                               const unsigned* __restrict__ bsums,
                               int* __restrict__ out) {
  int idx = blockIdx.x * 256 + threadIdx.x;
  if (idx >= 5 * NPTS) return;
  int s = idx / NPTS;
  int r = idx - s * NPTS;
  unsigned uniq = region_count(s, wp, bsums);
  if ((unsigned)r < uniq) return;
  ((int4*)(out + (size_t)s * OUT_STRIDE + 5 * NPTS))[r] =
      make_int4(-1, kSZ[s] - 1, kSY[s] - 1, kSX[s] - 1);
}

// ---- scatter: decompose each present key into coors[rank]
__global__ void scatter_kernel(const unsigned* __restrict__ bits,
                               const unsigned* __restrict__ wp,
                               const unsigned* __restrict__ bsums,
                               int* __restrict__ out) {
  int w = blockIdx.x * 256 + threadIdx.x;
  if (w >= W_TOTAL) return;
  unsigned word = bits[w];
  if (!word) return;
  int s, wb;
  unsigned sx, sy, sz;
  if      (w >= kWB[4]) { s = 4; wb = kWB[4]; sx = 481; sy = 361; sz = 33; }
  else if (w >= kWB[3]) { s = 3; wb = kWB[3]; sx = 31;  sy = 24;  sz = 3;  }
  else if (w >= kWB[2]) { s = 2; wb = kWB[2]; sx = 61;  sy = 46;  sz = 5;  }
  else if (w >= kWB[1]) { s = 1; wb = kWB[1]; sx = 121; sy = 91;  sz = 9;  }
  else                  { s = 0; wb = 0;      sx = 241; sy = 181; sz = 17; }
  unsigned rank = fullp(wp, bsums, w) - fullp(wp, bsums, wb);
  int4* coors = (int4*)(out + (size_t)s * OUT_STRIDE + 5 * NPTS);
  unsigned kbase = (unsigned)(w - wb) * 32u;
  while (word) {
    int bit = __ffs(word) - 1;
    word &= word - 1;
    unsigned k = kbase + (unsigned)bit;
    unsigned z = k % sz; unsigned t = k / sz;
    unsigned y = t % sy; t /= sy;
    unsigned x = t % sx; unsigned b = t / sx;
    coors[rank++] = make_int4((int)b, (int)z, (int)y, (int)x);
  }
}

// ---- inverse: recompute keys from points, rank via bitmap prefix
__global__ void inv_kernel(const float4* __restrict__ pts,
                           const int* __restrict__ bidx,
                           const unsigned* __restrict__ bits,
                           const unsigned* __restrict__ wp,
                           const unsigned* __restrict__ bsums,
                           int* __restrict__ out) {
  int i = blockIdx.x * blockDim.x + threadIdx.x;
  if (i >= NPTS) return;
  float4 p = pts[i];
  float rho = __fsqrt_rn(__fadd_rn(__fmul_rn(p.x, p.x), __fmul_rn(p.y, p.y)));
  float phi = (float)atan2((double)p.y, (double)p.x);
  float zz = p.z;
  int b = bidx[i];
  const float PI_F = 3.14159265f;
  const float CROP1 = PI_F + PI_F;
#pragma unroll
  for (int s = 0; s < 5; ++s) {
    int ix = (int)__fdiv_rn(__fmul_rn(kSSX[s], rho), 50.0f);
    int iy = (int)__fdiv_rn(__fmul_rn(kSSY[s], __fsub_rn(phi, -PI_F)), CROP1);
    int iz = (int)__fdiv_rn(__fmul_rn(kSSZ[s], __fsub_rn(zz, -4.0f)), 6.0f);
    unsigned k = (unsigned)(((b * kSX[s] + ix) * kSY[s] + iy) * kSZ[s] + iz);
    int w = kWB[s] + (int)(k >> 5);
    unsigned r = fullp(wp, bsums, w) - fullp(wp, bsums, kWB[s]) +
                 (unsigned)__popc(bits[w] & ((1u << (k & 31)) - 1u));
    out[(size_t)s * OUT_STRIDE + 4 * NPTS + i] = (int)r;
  }
}

extern "C" void kernel_launch(void* const* d_in, const int* in_sizes, int n_in,
                              void* d_out, int out_size, void* d_ws, size_t ws_size,
                              hipStream_t stream) {
  const float4* pts = (const float4*)d_in[0];
  const int* bidx = (const int*)d_in[1];
  int* out = (int*)d_out;

  unsigned* bits  = (unsigned*)d_ws;          // W_TOTAL u32 (3.3 MB)
  unsigned* wp    = bits + W_TOTAL;           // W_TOTAL u32 (3.3 MB)
  unsigned* bsums = wp + W_TOTAL;             // 1024 u32 ([512] = grand total)
  unsigned* priv  = bsums + 1024;             // MF_NB*LWT u32 (14.8 MB)
  unsigned char* bytemap = (unsigned char*)(priv + (size_t)MF_NB * LWT);  // 25.9 MB
  // total ws use: 47.2 MB (< 56.1 MB proven available in R2)

  zero_kernel<<<(BM_U4 + 255) / 256, 256, 0, stream>>>((uint4*)bytemap);
  mark_fill2_kernel<<<MF_NB, MF_BLK, 0, stream>>>(pts, bidx, out, bytemap, priv);
  reduce_kernel<<<(LWT + 255) / 256, 256, 0, stream>>>(priv, bits);
  scan1_kernel<<<SCAN_BLOCKS, 256, 0, stream>>>((const uint4*)bytemap, bits, wp, bsums);
  scan2_kernel<<<1, 1024, 0, stream>>>(bsums);
  padfill_kernel<<<(5 * NPTS + 255) / 256, 256, 0, stream>>>(wp, bsums, out);
  scatter_kernel<<<(W_TOTAL + 255) / 256, 256, 0, stream>>>(bits, wp, bsums, out);
  inv_kernel<<<(NPTS + 255) / 256, 256, 0, stream>>>(pts, bidx, bits, wp, bsums, out);
}

// Round 6
// 122.665 us; speedup vs baseline: 1.5055x; 1.1400x over previous
//
#include <hip/hip_runtime.h>

#define NPTS 1000000
#define OUT_STRIDE (9 * NPTS)

// Scales order: [2, 4, 8, 16, 1]; dims = ceil(SPATIAL/scale)+1
constexpr int   kSX[5]  = {241, 121, 61, 31, 481};
constexpr int   kSY[5]  = {181,  91, 46, 24, 361};
constexpr int   kSZ[5]  = { 17,   9,  5,  3,  33};
constexpr float kSSX[5] = {240.f, 120.f, 60.f, 30.f, 480.f};
constexpr float kSSY[5] = {180.f,  90.f, 45.f, 23.f, 360.f};
constexpr float kSSZ[5] = { 16.f,   8.f,  4.f,  2.f,  32.f};
// word-bases of each scale's bitmap region (keyspace/32, rounded up to 64)
constexpr int kWB[5] = {0, 92736, 105152, 106944, 107264};
#define W_TOTAL 823552        // 107264 + 716288
#define SCAN_BLOCKS 403       // ceil(W_TOTAL / 2048)

// byte map = exact 32x expansion of the bit map: byte index = word*32 + bit.
// Pad words between regions are never written -> stay 0 -> bits 0.
#define BM_BYTES ((size_t)W_TOTAL * 32)     // 26,353,664 B
#define BM_U4    (BM_BYTES / 16)            // 1,647,104 uint4

// emit kernel block ranges (256 threads each)
#define SCAT_BLOCKS 3217    // ceil(W_TOTAL / 256)
#define PAD_BLOCKS  19532   // ceil(5*NPTS / 256)
#define INV_BLOCKS  3907    // ceil(NPTS / 256)
#define EMIT_BLOCKS (SCAT_BLOCKS + PAD_BLOCKS + INV_BLOCKS)

// ---- zero the byte map
__global__ void zero_kernel(uint4* __restrict__ p) {
  size_t i = (size_t)blockIdx.x * 256 + threadIdx.x;
  if (i < BM_U4) p[i] = make_uint4(0u, 0u, 0u, 0u);
}

// ---- mark: compute polar once, write bxyz (coalesced) + 5 idempotent byte
//      stores (race-benign: all writers store 1). No LDS -> full occupancy.
__global__ void mark_kernel(const float4* __restrict__ pts,
                            const int* __restrict__ bidx,
                            int* __restrict__ out,
                            unsigned char* __restrict__ bytemap) {
  int i = blockIdx.x * 256 + threadIdx.x;
  if (i >= NPTS) return;
  float4 p = pts[i];
  float rho = __fsqrt_rn(__fadd_rn(__fmul_rn(p.x, p.x), __fmul_rn(p.y, p.y)));
  float phi = (float)atan2((double)p.y, (double)p.x);
  float zz = p.z;
  int b = bidx[i];
  const float PI_F = 3.14159265f;
  const float CROP1 = PI_F + PI_F;
#pragma unroll
  for (int s = 0; s < 5; ++s) {
    int ix = (int)__fdiv_rn(__fmul_rn(kSSX[s], rho), 50.0f);
    int iy = (int)__fdiv_rn(__fmul_rn(kSSY[s], __fsub_rn(phi, -PI_F)), CROP1);
    int iz = (int)__fdiv_rn(__fmul_rn(kSSZ[s], __fsub_rn(zz, -4.0f)), 6.0f);
    int key = ((b * kSX[s] + ix) * kSY[s] + iy) * kSZ[s] + iz;
    ((int4*)(out + (size_t)s * OUT_STRIDE))[i] = make_int4(b, ix, iy, iz);
    bytemap[(size_t)kWB[s] * 32 + (unsigned)key] = 1;
  }
}

// 32 presence-bytes (each 0/1) -> 32-bit mask
__device__ __forceinline__ unsigned nib(unsigned u) {
  return (u | (u >> 7) | (u >> 14) | (u >> 21)) & 0xFu;
}
__device__ __forceinline__ unsigned word_from_bytes(const uint4* p) {
  uint4 a = p[0], b = p[1];
  return nib(a.x) | (nib(a.y) << 4) | (nib(a.z) << 8) | (nib(a.w) << 12) |
         (nib(b.x) << 16) | (nib(b.y) << 20) | (nib(b.z) << 24) | (nib(b.w) << 28);
}

// ---- scan stage 1: bytes -> bit words (uniform) + popcount block prefix
__global__ void scan1_kernel(const uint4* __restrict__ bytemap,
                             unsigned* __restrict__ bits,
                             unsigned* __restrict__ wp,
                             unsigned* __restrict__ bsums) {
  __shared__ unsigned sh[256];
  int tid = threadIdx.x;
  int base = blockIdx.x * 2048 + tid * 8;
  unsigned c[8];
  unsigned sum = 0;
#pragma unroll
  for (int j = 0; j < 8; ++j) {
    c[j] = sum;
    int w = base + j;
    unsigned m = 0;
    if (w < W_TOTAL) {
      m = word_from_bytes(bytemap + (size_t)w * 2);
      bits[w] = m;
    }
    sum += (unsigned)__popc(m);
  }
  sh[tid] = sum;
  __syncthreads();
  for (int off = 1; off < 256; off <<= 1) {
    unsigned v = (tid >= off) ? sh[tid - off] : 0u;
    __syncthreads();
    sh[tid] += v;
    __syncthreads();
  }
  unsigned tbase = sh[tid] - sum;
#pragma unroll
  for (int j = 0; j < 8; ++j) {
    int w = base + j;
    if (w < W_TOTAL) wp[w] = tbase + c[j];
  }
  if (tid == 0) bsums[blockIdx.x] = sh[255];
}

// ---- scan stage 2: exclusive scan of block sums; also store grand total
__global__ void scan2_kernel(unsigned* __restrict__ bsums) {
  __shared__ unsigned sh[1024];
  int t = threadIdx.x;
  unsigned v = (t < SCAN_BLOCKS) ? bsums[t] : 0u;
  sh[t] = v;
  __syncthreads();
  for (int off = 1; off < 1024; off <<= 1) {
    unsigned u = (t >= off) ? sh[t - off] : 0u;
    __syncthreads();
    sh[t] += u;
    __syncthreads();
  }
  if (t < SCAN_BLOCKS) bsums[t] = sh[t] - v;  // exclusive
  if (t == SCAN_BLOCKS - 1) bsums[512] = sh[t];  // inclusive grand total
}

// full prefix of word w = wp[w] + bsums[w >> 11]
__device__ __forceinline__ unsigned fullp(const unsigned* wp, const unsigned* bs, int w) {
  return wp[w] + bs[w >> 11];
}

__device__ __forceinline__ unsigned region_count(int s, const unsigned* wp,
                                                 const unsigned* bs) {
  unsigned lo = fullp(wp, bs, kWB[s]);
  unsigned hi = (s == 4) ? bs[512] : fullp(wp, bs, kWB[s + 1]);
  return hi - lo;
}

// ---- emit: fused scatter / padfill / inverse (all depend only on scan2)
__global__ void emit_kernel(const float4* __restrict__ pts,
                            const int* __restrict__ bidx,
                            const unsigned* __restrict__ bits,
                            const unsigned* __restrict__ wp,
                            const unsigned* __restrict__ bsums,
                            int* __restrict__ out) {
  int blk = blockIdx.x;
  if (blk < SCAT_BLOCKS) {
    // --- scatter: decompose each present key into coors[rank]
    int w = blk * 256 + threadIdx.x;
    if (w >= W_TOTAL) return;
    unsigned word = bits[w];
    if (!word) return;
    int s, wb;
    unsigned sx, sy, sz;
    if      (w >= kWB[4]) { s = 4; wb = kWB[4]; sx = 481; sy = 361; sz = 33; }
    else if (w >= kWB[3]) { s = 3; wb = kWB[3]; sx = 31;  sy = 24;  sz = 3;  }
    else if (w >= kWB[2]) { s = 2; wb = kWB[2]; sx = 61;  sy = 46;  sz = 5;  }
    else if (w >= kWB[1]) { s = 1; wb = kWB[1]; sx = 121; sy = 91;  sz = 9;  }
    else                  { s = 0; wb = 0;      sx = 241; sy = 181; sz = 17; }
    unsigned rank = fullp(wp, bsums, w) - fullp(wp, bsums, wb);
    int4* coors = (int4*)(out + (size_t)s * OUT_STRIDE + 5 * NPTS);
    unsigned kbase = (unsigned)(w - wb) * 32u;
    while (word) {
      int bit = __ffs(word) - 1;
      word &= word - 1;
      unsigned k = kbase + (unsigned)bit;
      unsigned z = k % sz; unsigned t = k / sz;
      unsigned y = t % sy; t /= sy;
      unsigned x = t % sx; unsigned b = t / sx;
      coors[rank++] = make_int4((int)b, (int)z, (int)y, (int)x);
    }
  } else if (blk < SCAT_BLOCKS + PAD_BLOCKS) {
    // --- pad fill: rows >= uniq_count get the fill_value=-1 decode
    int idx = (blk - SCAT_BLOCKS) * 256 + threadIdx.x;
    if (idx >= 5 * NPTS) return;
    int s = idx / NPTS;
    int r = idx - s * NPTS;
    unsigned uniq = region_count(s, wp, bsums);
    if ((unsigned)r < uniq) return;
    ((int4*)(out + (size_t)s * OUT_STRIDE + 5 * NPTS))[r] =
        make_int4(-1, kSZ[s] - 1, kSY[s] - 1, kSX[s] - 1);
  } else {
    // --- inverse: recompute keys from points, rank via bitmap prefix
    int i = (blk - SCAT_BLOCKS - PAD_BLOCKS) * 256 + threadIdx.x;
    if (i >= NPTS) return;
    float4 p = pts[i];
    float rho = __fsqrt_rn(__fadd_rn(__fmul_rn(p.x, p.x), __fmul_rn(p.y, p.y)));
    float phi = (float)atan2((double)p.y, (double)p.x);
    float zz = p.z;
    int b = bidx[i];
    const float PI_F = 3.14159265f;
    const float CROP1 = PI_F + PI_F;
#pragma unroll
    for (int s = 0; s < 5; ++s) {
      int ix = (int)__fdiv_rn(__fmul_rn(kSSX[s], rho), 50.0f);
      int iy = (int)__fdiv_rn(__fmul_rn(kSSY[s], __fsub_rn(phi, -PI_F)), CROP1);
      int iz = (int)__fdiv_rn(__fmul_rn(kSSZ[s], __fsub_rn(zz, -4.0f)), 6.0f);
      unsigned k = (unsigned)(((b * kSX[s] + ix) * kSY[s] + iy) * kSZ[s] + iz);
      int w = kWB[s] + (int)(k >> 5);
      unsigned r = fullp(wp, bsums, w) - fullp(wp, bsums, kWB[s]) +
                   (unsigned)__popc(bits[w] & ((1u << (k & 31)) - 1u));
      out[(size_t)s * OUT_STRIDE + 4 * NPTS + i] = (int)r;
    }
  }
}

extern "C" void kernel_launch(void* const* d_in, const int* in_sizes, int n_in,
                              void* d_out, int out_size, void* d_ws, size_t ws_size,
                              hipStream_t stream) {
  const float4* pts = (const float4*)d_in[0];
  const int* bidx = (const int*)d_in[1];
  int* out = (int*)d_out;

  unsigned* bits  = (unsigned*)d_ws;          // W_TOTAL u32 (3.3 MB)
  unsigned* wp    = bits + W_TOTAL;           // W_TOTAL u32 (3.3 MB)
  unsigned* bsums = wp + W_TOTAL;             // 1024 u32 ([512] = grand total)
  unsigned char* bytemap = (unsigned char*)(bsums + 1024);  // 26.4 MB
  // total ws use: ~33 MB (< 47.2 MB proven available in R5)

  zero_kernel<<<(int)((BM_U4 + 255) / 256), 256, 0, stream>>>((uint4*)bytemap);
  mark_kernel<<<(NPTS + 255) / 256, 256, 0, stream>>>(pts, bidx, out, bytemap);
  scan1_kernel<<<SCAN_BLOCKS, 256, 0, stream>>>((const uint4*)bytemap, bits, wp, bsums);
  scan2_kernel<<<1, 1024, 0, stream>>>(bsums);
  emit_kernel<<<EMIT_BLOCKS, 256, 0, stream>>>(pts, bidx, bits, wp, bsums, out);
}